// Round 2
// baseline (167.708 us; speedup 1.0000x reference)
//
#include <hip/hip_runtime.h>
#include <math.h>

// Problem constants (from reference): inputs/targets [32, 8, 256, 256] fp32.
constexpr int B_ = 32;
constexpr int C_ = 8;
constexpr int HW_ = 256 * 256;          // 65536
constexpr float FEPS = 1e-6f;
constexpr float NUM_COLS = 8.0f * 65536.0f;  // 524288

// Grid: 512 blocks x 256 threads (2 blocks/CU, 8 waves/CU).
// Block covers 128 consecutive hw (64 lanes x 2 hw each, float2 loads)
// and all 32 batches (4 batch-groups of 8, one per wave).
__global__ __launch_bounds__(256) void dice_main(const float* __restrict__ in,
                                                 const float* __restrict__ tg,
                                                 float* __restrict__ accum) {
    const int tid  = threadIdx.x;
    const int lane = tid & 63;
    const int bg   = tid >> 6;                 // 0..3 (one wave each)
    const int hw0  = blockIdx.x * 128 + lane * 2;

    // accumulators: [v in {0,1} sub-hw][c]
    float inter[2][8];
    float den[2][8];
#pragma unroll
    for (int v = 0; v < 2; ++v)
#pragma unroll
        for (int c = 0; c < 8; ++c) { inter[v][c] = 0.0f; den[v][c] = 0.0f; }

#pragma unroll
    for (int bi = 0; bi < 8; ++bi) {
        const int b = bg * 8 + bi;
        const int base = (b * C_) * HW_ + hw0;   // < 2^24, int math is safe

        // Issue ALL 16 loads (8 in + 8 tg) before any compute: 16 x 8 B/lane
        // in flight per wave -> latency hiding does not depend on occupancy.
        float2 xv[8], tv[8];
#pragma unroll
        for (int c = 0; c < 8; ++c) {
            xv[c] = *reinterpret_cast<const float2*>(in + base + c * HW_);
            tv[c] = *reinterpret_cast<const float2*>(tg + base + c * HW_);
        }

        float m0 = xv[0].x, m1 = xv[0].y;
#pragma unroll
        for (int c = 1; c < 8; ++c) { m0 = fmaxf(m0, xv[c].x); m1 = fmaxf(m1, xv[c].y); }

        float e0[8], e1[8];
        float s0 = 0.0f, s1 = 0.0f;
#pragma unroll
        for (int c = 0; c < 8; ++c) {
            e0[c] = __expf(xv[c].x - m0); s0 += e0[c];
            e1[c] = __expf(xv[c].y - m1); s1 += e1[c];
        }
        const float r0 = 1.0f / s0;
        const float r1 = 1.0f / s1;

#pragma unroll
        for (int c = 0; c < 8; ++c) {
            const float p0 = e0[c] * r0;
            const float p1 = e1[c] * r1;
            inter[0][c] = fmaf(p0, tv[c].x, inter[0][c]);
            inter[1][c] = fmaf(p1, tv[c].y, inter[1][c]);
            den[0][c] += p0 + tv[c].x;
            den[1][c] += p1 + tv[c].y;
        }
    }

    // Cross-batch-group reduction through LDS.
    // Layout [bg][lane][34]: 16 inter + 16 den + 2 pad (stride 34 -> lane*34
    // mod 32 = lane*2 -> 2-way conflict = free per m136).
    __shared__ float red[4][64][34];
#pragma unroll
    for (int v = 0; v < 2; ++v)
#pragma unroll
        for (int c = 0; c < 8; ++c) {
            red[bg][lane][v * 8 + c]      = inter[v][c];
            red[bg][lane][16 + v * 8 + c] = den[v][c];
        }
    __syncthreads();

    // 1024 columns per block; each of the 256 threads finishes 4 columns.
    float part = 0.0f;
#pragma unroll
    for (int i = 0; i < 4; ++i) {
        const int j   = tid * 4 + i;     // 0..1023
        const int lj  = j >> 4;
        const int idx = j & 15;
        const float it = red[0][lj][idx] + red[1][lj][idx] +
                         red[2][lj][idx] + red[3][lj][idx];
        const float dn = red[0][lj][16 + idx] + red[1][lj][16 + idx] +
                         red[2][lj][16 + idx] + red[3][lj][16 + idx];
        part += (2.0f * it + FEPS) / (dn + FEPS);
    }

    // wave64 reduce, then cross-wave via LDS, one atomicAdd per block.
#pragma unroll
    for (int off = 32; off > 0; off >>= 1)
        part += __shfl_down(part, off, 64);

    __shared__ float wsum[4];
    if (lane == 0) wsum[bg] = part;
    __syncthreads();
    if (tid == 0)
        atomicAdd(accum, wsum[0] + wsum[1] + wsum[2] + wsum[3]);
}

__global__ void dice_final(const float* __restrict__ accum, float* __restrict__ out) {
    out[0] = 1.0f - accum[0] * (1.0f / NUM_COLS);
}

extern "C" void kernel_launch(void* const* d_in, const int* in_sizes, int n_in,
                              void* d_out, int out_size, void* d_ws, size_t ws_size,
                              hipStream_t stream) {
    const float* in = (const float*)d_in[0];
    const float* tg = (const float*)d_in[1];
    float* out = (float*)d_out;
    float* acc = (float*)d_ws;

    // d_ws is re-poisoned to 0xAA before every timed launch -> zero it here.
    hipMemsetAsync(acc, 0, sizeof(float), stream);
    dice_main<<<dim3(HW_ / 128), dim3(256), 0, stream>>>(in, tg, acc);
    dice_final<<<1, 1, 0, stream>>>(acc, out);
}